// Round 18
// baseline (84.056 us; speedup 1.0000x reference)
//
#include <hip/hip_runtime.h>
#include <hip/hip_bf16.h>
#include <math.h>

#define NSEQ   4096
#define CDIM   128
#define HD     32

typedef __attribute__((ext_vector_type(8))) short short8;
typedef __attribute__((ext_vector_type(4))) short short4v;
typedef __attribute__((ext_vector_type(4))) float f32x4;

#define QSCL (0.17677669529663687f * 1.4426950408889634f)  // 1/sqrt(32)*log2(e)

__device__ inline unsigned short f2bf(float f){
  union { float f; unsigned u; } v; v.f = f;
  return (unsigned short)((v.u + 0x7fffu + ((v.u >> 16) & 1u)) >> 16);
}
__device__ inline float bf2f(unsigned short u){
  union { unsigned u; float f; } v; v.u = ((unsigned)u) << 16;
  return v.f;
}
__device__ inline void gload_lds16(const unsigned short* g, unsigned short* l){
  __builtin_amdgcn_global_load_lds(
      (const __attribute__((address_space(1))) void*)g,
      (__attribute__((address_space(3))) void*)l, 16, 0, 0);
}

// ---- ws layout (bytes) -----------------------------------------------------
// 0        : wpack u16 [196608] (wq@0, wp@49152, w1@65536, w2@131072)
// 393216   : bqs f32 [384]
// 524288   : qkv u16 48 planes x 131072 (Q[0..15] rowmajor, Kfrag[16..31], Vfrag[32..47])
// 13107200 : attnA u16 [16384/16][2048]  (4.19MB; normalized attn out,
//            proj-A-fragment layout: idx = (tok>>4)*2048 + (col>>3)*128
//            + (tok&15)*8 + (col&7), col = h*32 + d)

// ---------------- K0: pack weights to MFMA B-fragment layout ----------------
__global__ __launch_bounds__(256) void k_pack(
    const float* __restrict__ qkv_w, const float* __restrict__ qkv_b,
    const float* __restrict__ proj_w, const float* __restrict__ mlp_w1,
    const float* __restrict__ mlp_w2, unsigned short* __restrict__ wpack,
    float* __restrict__ bqs)
{
  const int gt = blockIdx.x * 256 + threadIdx.x;
  const int tile = gt >> 6, lane = gt & 63;
  const float* src; int N, KT, toff, dstoff; float scale = 1.f;
  if (tile < 96)       { src = qkv_w;  N = 384; KT = 4;  toff = tile;       dstoff = 0; }
  else if (tile < 128) { src = proj_w; N = 128; KT = 4;  toff = tile - 96;  dstoff = 49152; }
  else if (tile < 256) { src = mlp_w1; N = 512; KT = 4;  toff = tile - 128; dstoff = 65536; }
  else                 { src = mlp_w2; N = 128; KT = 16; toff = tile - 256; dstoff = 131072; }
  const int ct = toff / KT, kt = toff % KT;
  if (tile < 96 && ct < 8) scale = QSCL;   // Q columns
  const int row0 = kt * 32 + (lane >> 4) * 8, col = ct * 16 + (lane & 15);
  short8 v;
  #pragma unroll
  for (int i = 0; i < 8; i++)
    v[i] = (short)f2bf(src[(size_t)(row0 + i) * N + col] * scale);
  *(short8*)(wpack + dstoff + ((size_t)(ct * KT + kt) * 64 + lane) * 8) = v;
  if (gt < 384) bqs[gt] = qkv_b[gt] * (gt < 128 ? QSCL : 1.f);
}

// ---------------- K1: LN1 + QKV MFMA GEMM (64 tokens/block, 256 blocks) -----
__global__ __launch_bounds__(512) void k_qkv(
    const float* __restrict__ x, const float* __restrict__ g,
    const float* __restrict__ b, const unsigned short* __restrict__ wpack,
    const float* __restrict__ bqs, unsigned short* __restrict__ qkv)
{
  __shared__ unsigned short xn[64 * 128];
  const int tid = threadIdx.x;
  const int tok0 = blockIdx.x * 64;
  {
    const int grp = tid >> 5, l = tid & 31;
    #pragma unroll
    for (int it = 0; it < 4; it++){
      const int t = it * 16 + grp;
      const float4 xv = *(const float4*)(x + (size_t)(tok0 + t) * 128 + l * 4);
      float s  = xv.x + xv.y + xv.z + xv.w;
      float s2 = xv.x*xv.x + xv.y*xv.y + xv.z*xv.z + xv.w*xv.w;
      #pragma unroll
      for (int m = 1; m <= 16; m <<= 1){ s += __shfl_xor(s, m); s2 += __shfl_xor(s2, m); }
      const float mu = s * (1.f/128.f);
      const float rs = rsqrtf(s2 * (1.f/128.f) - mu*mu + 1e-5f);
      const int e = l * 4;
      const float4 gv = *(const float4*)(g + e), bv = *(const float4*)(b + e);
      short4v pk;
      pk[0] = (short)f2bf((xv.x - mu)*rs*gv.x + bv.x);
      pk[1] = (short)f2bf((xv.y - mu)*rs*gv.y + bv.y);
      pk[2] = (short)f2bf((xv.z - mu)*rs*gv.z + bv.z);
      pk[3] = (short)f2bf((xv.w - mu)*rs*gv.w + bv.w);
      const int bl = l >> 1;
      const int slot = bl * 64 + (t & 48) + ((t & 15) ^ bl);
      *(short4v*)(xn + slot * 8 + (l & 1) * 4) = pk;
    }
  }
  __syncthreads();
  const int wv = tid >> 6, lane = tid & 63, r = lane & 15, cg = lane >> 4;
  const int rt = wv & 3, ct0 = (wv >> 2) * 12;
  short8 af[4];
  #pragma unroll
  for (int kt = 0; kt < 4; kt++){
    const int bl = kt * 4 + cg;
    const int slot = bl * 64 + rt * 16 + (r ^ bl);
    af[kt] = *(const short8*)(xn + slot * 8);
  }
  const int bidx = tok0 >> 12, nloc = (tok0 & (NSEQ - 1)) + rt * 16 + cg * 4;
  for (int ct = ct0; ct < ct0 + 12; ct++){
    f32x4 acc = {0.f, 0.f, 0.f, 0.f};
    const unsigned short* bp = wpack + ((size_t)(ct * 4) * 64 + lane) * 8;
    #pragma unroll
    for (int kt = 0; kt < 4; kt++)
      acc = __builtin_amdgcn_mfma_f32_16x16x32_bf16(af[kt], *(const short8*)(bp + kt * 512), acc, 0, 0, 0);
    const int col = ct * 16 + r;
    const float bi = bqs[col];
    if (ct < 8){                                   // Q: row-major [n][32]
      const int cc = col & 127, h = cc >> 5, d = cc & 31;
      unsigned short* plane = qkv + ((size_t)bidx * 4 + h) * (NSEQ * HD);
      #pragma unroll
      for (int reg = 0; reg < 4; reg++)
        plane[(size_t)(nloc + reg) * HD + d] = f2bf(acc[reg] + bi);
    } else if (ct < 16){                           // K: A-fragment layout per 16-row tile
      const int cc = col & 127, h = cc >> 5, d = cc & 31;
      unsigned short* plane = qkv + ((size_t)16 + bidx * 4 + h) * (NSEQ * HD);
      const int t16 = ((tok0 & (NSEQ - 1)) >> 4) + rt;
      #pragma unroll
      for (int reg = 0; reg < 4; reg++)
        plane[(size_t)t16 * 512 + (d >> 3) * 128 + (cg * 4 + reg) * 8 + (d & 7)]
            = f2bf(acc[reg] + bi);
    } else {                                       // V: PV-fragment layout
      const int vct = ct - 16, h = vct >> 1, half = vct & 1;
      unsigned short* plane = qkv + ((size_t)32 + bidx * 4 + h) * (NSEQ * HD);
      const size_t ntile = (size_t)((tok0 & (NSEQ - 1)) >> 5) + (rt >> 1);
      const size_t vo = (ntile * 2 + half) * 512 + lane * 8 + (rt & 1) * 4;
      short4v pk;
      #pragma unroll
      for (int reg = 0; reg < 4; reg++) pk[reg] = (short)f2bf(acc[reg] + bi);
      *(short4v*)(plane + vo) = pk;
    }
  }
}

// ---------------- K2: flash attention, full sweep, KVBLK=128 ----------------
// 512 blocks (1D, XCD-swizzled: 2 bh per XCD -> K/V L2-resident), 512 thr
// (8 waves x 16 q-rows = 128 q-rows/block). 64KB LDS ring (4 slots x 16KB),
// 2 blocks/CU -> 16 waves/CU; 20 MFMA + 32 exp per barrier (r12-proven
// density). Each wave stages 2x1KB per iter -> counted wait vmcnt(4).
// No KV split: normalized output written directly in proj-A-frag layout.
__global__ __launch_bounds__(512) void k_attn(
    const unsigned short* __restrict__ qkv, unsigned short* __restrict__ attnA)
{
  __shared__ unsigned short sbuf[32768];   // 64KB: 4 slots x (K 8KB + V 8KB)
  const int tid = threadIdx.x;
  const int lane = tid & 63, wv = tid >> 6;
  const int id = blockIdx.x;
  const int xcd = id & 7, seq = id >> 3;          // seq 0..63
  const int bh = xcd * 2 + (seq >> 5);            // 2 bh per XCD
  const int qbase = (seq & 31) * 128 + wv * 16;   // 16 q-rows per wave
  const unsigned short* Q  = qkv + (size_t)bh * (NSEQ * HD);
  const unsigned short* Kc = qkv + (size_t)(16 + bh) * (NSEQ * HD);
  const unsigned short* Vc = qkv + (size_t)(32 + bh) * (NSEQ * HD);
  const int r = lane & 15, cg = lane >> 4;
  const short8 qf0 = *(const short8*)(Q + (size_t)(qbase + r) * HD + cg * 8);
  // staging: per iter (128 keys = 16KB) wave w loads K-chunk w (1KB) and
  // V-chunk w (1KB). K plane tile stride 512 u16; V ntile stride 1024 u16;
  // both reduce to byte-offset (8t + w)*512 u16 for iter t.
  const unsigned short* gK = Kc + lane * 8;
  const unsigned short* gV = Vc + lane * 8;
  const int dK = wv * 512, dV = 4096 + wv * 512;  // u16 offsets within slot
  union { unsigned u[4]; short8 s; } onesu;
  onesu.u[0] = 0x3F803F80u; onesu.u[1] = 0x3F803F80u;
  onesu.u[2] = 0x3F803F80u; onesu.u[3] = 0x3F803F80u;
  const short8 vones = onesu.s;
  f32x4 o00 = {0.f,0.f,0.f,0.f}, o01 = {0.f,0.f,0.f,0.f};
  f32x4 lacc = {0.f,0.f,0.f,0.f};
  const f32x4 zero = {0.f,0.f,0.f,0.f};
  // prologue: 3-deep prefetch (slots 0,1,2); per slot K then V
  #pragma unroll
  for (int s = 0; s < 3; s++){
    gload_lds16(gK + (size_t)(8 * s + wv) * 512, sbuf + s * 8192 + dK);
    gload_lds16(gV + (size_t)(8 * s + wv) * 512, sbuf + s * 8192 + dV);
  }
  for (int t = 0; t < 32; t++){
    // own K/V of iter t landed (vmcnt(4): exactly 6 outstanding, oldest 2
    // are iter t's) AND own prior-iter LDS reads done, BEFORE the barrier.
    asm volatile("s_waitcnt vmcnt(4) lgkmcnt(0)" ::: "memory");
    __builtin_amdgcn_sched_barrier(0);
    __builtin_amdgcn_s_barrier();
    __builtin_amdgcn_sched_barrier(0);
    const int tn = (t + 3 > 31) ? 31 : t + 3;   // clamped dummy keeps vmcnt uniform
    gload_lds16(gK + (size_t)(8 * tn + wv) * 512, sbuf + ((t + 3) & 3) * 8192 + dK);
    gload_lds16(gV + (size_t)(8 * tn + wv) * 512, sbuf + ((t + 3) & 3) * 8192 + dV);
    const unsigned short* skb = sbuf + (t & 3) * 8192;
    const unsigned short* svb = skb + 4096;
    #pragma unroll
    for (int ktp = 0; ktp < 4; ktp++){
      const short8 kaa = *(const short8*)(skb + (ktp * 2 + 0) * 512 + lane * 8);
      const short8 kab = *(const short8*)(skb + (ktp * 2 + 1) * 512 + lane * 8);
      const short8 va0 = *(const short8*)(svb + ktp * 1024 + lane * 8);
      const short8 va1 = *(const short8*)(svb + ktp * 1024 + 512 + lane * 8);
      const f32x4 s00 = __builtin_amdgcn_mfma_f32_16x16x32_bf16(kaa, qf0, zero, 0, 0, 0);
      const f32x4 s01 = __builtin_amdgcn_mfma_f32_16x16x32_bf16(kab, qf0, zero, 0, 0, 0);
      float p0[4], p1[4];
      #pragma unroll
      for (int i = 0; i < 4; i++){
        p0[i] = __builtin_amdgcn_exp2f(s00[i]);
        p1[i] = __builtin_amdgcn_exp2f(s01[i]);
      }
      unsigned c0, c1, c2, c3;
      asm("v_cvt_pk_bf16_f32 %0, %1, %2" : "=v"(c0) : "v"(p0[0]), "v"(p0[1]));
      asm("v_cvt_pk_bf16_f32 %0, %1, %2" : "=v"(c1) : "v"(p0[2]), "v"(p0[3]));
      asm("v_cvt_pk_bf16_f32 %0, %1, %2" : "=v"(c2) : "v"(p1[0]), "v"(p1[1]));
      asm("v_cvt_pk_bf16_f32 %0, %1, %2" : "=v"(c3) : "v"(p1[2]), "v"(p1[3]));
      union { unsigned u[4]; short8 s; } pa;
      pa.u[0] = c0; pa.u[1] = c1; pa.u[2] = c2; pa.u[3] = c3;
      o00 = __builtin_amdgcn_mfma_f32_16x16x32_bf16(va0, pa.s, o00, 0, 0, 0);
      o01 = __builtin_amdgcn_mfma_f32_16x16x32_bf16(va1, pa.s, o01, 0, 0, 0);
      lacc = __builtin_amdgcn_mfma_f32_16x16x32_bf16(vones, pa.s, lacc, 0, 0, 0);
    }
  }
  // drain trailing dummy LDS-DMA writes before workgroup exit
  asm volatile("s_waitcnt vmcnt(0)" ::: "memory");
  const float inv = 1.f / lacc[0];
  // write normalized O in proj-A-fragment layout:
  // o00[j]: q=qbase+r, d = cg*4+j;  o01[j]: q=qbase+r, d = 16+cg*4+j.
  // col = h*32+d -> oct = col>>3 = h*4 + (d>>3), sub = (col&7) = (cg&1)*4+j.
  const int b = bh >> 2, h = bh & 3;
  unsigned short* pa = attnA + ((((size_t)b * NSEQ + qbase) >> 4) * 2048);
  short4v w0, w1;
  #pragma unroll
  for (int j = 0; j < 4; j++){
    w0[j] = (short)f2bf(o00[j] * inv);
    w1[j] = (short)f2bf(o01[j] * inv);
  }
  *(short4v*)(pa + (h * 4 + 0 + (cg >> 1)) * 128 + r * 8 + (cg & 1) * 4) = w0;
  *(short4v*)(pa + (h * 4 + 2 + (cg >> 1)) * 128 + r * 8 + (cg & 1) * 4) = w1;
}

// ---------------- K3: fused proj+LN2+MLP1+GELU+MLP2 (32 tok/block) ----------
__global__ __launch_bounds__(512, 6) void k_fused(
    const unsigned short* __restrict__ attnA, const float* __restrict__ x,
    const unsigned short* __restrict__ wpack, const float* __restrict__ pb,
    const float* __restrict__ g2, const float* __restrict__ b2,
    const float* __restrict__ b1, const float* __restrict__ b2m,
    float* __restrict__ out)
{
  __shared__ unsigned short afh[2][2048];    //  8KB LN2 output, A-frag layout
  __shared__ unsigned short sbb[32 * 128];   //  8KB residual, bf16
  __shared__ unsigned short afr[2][8192];    // 32KB GELU acts, A-frag layout
  const int tid = threadIdx.x, tok0 = blockIdx.x * 32;
  const int wv = tid >> 6, lane = tid & 63, r = lane & 15, cg = lane >> 4;
  const int rt = wv & 1, cgp = wv >> 1;
  // ---- phase A: proj MFMA + bias + residual -> sbb (bf16)
  {
    short8 af[4];
    const unsigned short* pa = attnA + ((size_t)((tok0 >> 4) + rt)) * 2048;
    #pragma unroll
    for (int kt = 0; kt < 4; kt++)
      af[kt] = *(const short8*)(pa + (kt * 4 + cg) * 128 + r * 8);
    const unsigned short* wp = wpack + 49152;
    for (int ct = cgp * 2; ct < cgp * 2 + 2; ct++){
      f32x4 acc = {0.f, 0.f, 0.f, 0.f};
      const unsigned short* bp = wp + ((size_t)(ct * 4) * 64 + lane) * 8;
      #pragma unroll
      for (int kt = 0; kt < 4; kt++)
        acc = __builtin_amdgcn_mfma_f32_16x16x32_bf16(af[kt], *(const short8*)(bp + kt * 512), acc, 0, 0, 0);
      const int col = ct * 16 + r;
      const float bi = pb[col];
      #pragma unroll
      for (int reg = 0; reg < 4; reg++){
        const int tl = rt * 16 + cg * 4 + reg;
        sbb[tl * 128 + col] = f2bf(acc[reg] + bi + x[(size_t)(tok0 + tl) * 128 + col]);
      }
    }
  }
  __syncthreads();
  // ---- phase B: LN2(sbb) -> afh (A-frag layout)
  {
    const int grp = tid >> 5, l = tid & 31;
    #pragma unroll
    for (int it = 0; it < 2; it++){
      const int t = it * 16 + grp;
      const short4v xb = *(const short4v*)(sbb + t * 128 + l * 4);
      const float x0 = bf2f((unsigned short)xb[0]), x1 = bf2f((unsigned short)xb[1]);
      const float x2 = bf2f((unsigned short)xb[2]), x3 = bf2f((unsigned short)xb[3]);
      float s  = x0 + x1 + x2 + x3;
      float s2 = x0*x0 + x1*x1 + x2*x2 + x3*x3;
      #pragma unroll
      for (int m = 1; m <= 16; m <<= 1){ s += __shfl_xor(s, m); s2 += __shfl_xor(s2, m); }
      const float mu = s * (1.f/128.f);
      const float rs = rsqrtf(s2 * (1.f/128.f) - mu*mu + 1e-5f);
      const int e = l * 4;
      const float4 gv = *(const float4*)(g2 + e), bv = *(const float4*)(b2 + e);
      short4v pk;
      pk[0] = (short)f2bf((x0 - mu)*rs*gv.x + bv.x);
      pk[1] = (short)f2bf((x1 - mu)*rs*gv.y + bv.y);
      pk[2] = (short)f2bf((x2 - mu)*rs*gv.z + bv.z);
      pk[3] = (short)f2bf((x3 - mu)*rs*gv.w + bv.w);
      *(short4v*)(&afh[t >> 4][(e >> 3) * 128 + (t & 15) * 8 + (e & 7)]) = pk;
    }
  }
  __syncthreads();
  // ---- phase C: MLP1 + GELU(tanh approx) -> afr (A-frag layout)
  {
    short8 hf[4];
    #pragma unroll
    for (int kt = 0; kt < 4; kt++)
      hf[kt] = *(const short8*)(&afh[rt][(kt * 4 + cg) * 128 + r * 8]);
    const unsigned short* w1 = wpack + 65536;
    for (int ct = cgp * 8; ct < cgp * 8 + 8; ct++){
      f32x4 acc = {0.f, 0.f, 0.f, 0.f};
      const unsigned short* bp = w1 + ((size_t)(ct * 4) * 64 + lane) * 8;
      #pragma unroll
      for (int kt = 0; kt < 4; kt++)
        acc = __builtin_amdgcn_mfma_f32_16x16x32_bf16(hf[kt], *(const short8*)(bp + kt * 512), acc, 0, 0, 0);
      const int col = ct * 16 + r;
      const float bi = b1[col];
      #pragma unroll
      for (int reg = 0; reg < 4; reg++){
        const float v = acc[reg] + bi;
        const float u = v * (2.3022077f + 0.10294324f * v * v);
        const float ge = v * __builtin_amdgcn_rcpf(1.f + __builtin_amdgcn_exp2f(-u));
        afr[rt][(col >> 3) * 128 + (cg * 4 + reg) * 8 + (col & 7)] = f2bf(ge);
      }
    }
  }
  __syncthreads();
  // ---- phase D: MLP2 + residual (sbb) -> out
  {
    const unsigned short* w2 = wpack + 131072;
    f32x4 acc0 = {0.f,0.f,0.f,0.f}, acc1 = {0.f,0.f,0.f,0.f};
    for (int kt = 0; kt < 16; kt++){
      const short8 a3 = *(const short8*)(&afr[rt][(kt * 4 + cg) * 128 + r * 8]);
      const unsigned short* bp0 = w2 + ((size_t)((cgp * 2 + 0) * 16 + kt) * 64 + lane) * 8;
      const unsigned short* bp1 = w2 + ((size_t)((cgp * 2 + 1) * 16 + kt) * 64 + lane) * 8;
      acc0 = __builtin_amdgcn_mfma_f32_16x16x32_bf16(a3, *(const short8*)(bp0), acc0, 0, 0, 0);
      acc1 = __builtin_amdgcn_mfma_f32_16x16x32_bf16(a3, *(const short8*)(bp1), acc1, 0, 0, 0);
    }
    #pragma unroll
    for (int c = 0; c < 2; c++){
      const f32x4 acc = c ? acc1 : acc0;
      const int col = (cgp * 2 + c) * 16 + r;
      const float bi = b2m[col];
      #pragma unroll
      for (int reg = 0; reg < 4; reg++){
        const int tl = rt * 16 + cg * 4 + reg;
        out[(size_t)(tok0 + tl) * 128 + col] = acc[reg] + bi + bf2f(sbb[tl * 128 + col]);
      }
    }
  }
}

extern "C" void kernel_launch(void* const* d_in, const int* in_sizes, int n_in,
                              void* d_out, int out_size, void* d_ws, size_t ws_size,
                              hipStream_t stream)
{
  const float* x      = (const float*)d_in[0];
  const float* ln1_g  = (const float*)d_in[1];
  const float* ln1_b  = (const float*)d_in[2];
  const float* qkv_w  = (const float*)d_in[3];
  const float* qkv_b  = (const float*)d_in[4];
  const float* proj_w = (const float*)d_in[5];
  const float* proj_b = (const float*)d_in[6];
  const float* ln2_g  = (const float*)d_in[7];
  const float* ln2_b  = (const float*)d_in[8];
  const float* mlp_w1 = (const float*)d_in[9];
  const float* mlp_b1 = (const float*)d_in[10];
  const float* mlp_w2 = (const float*)d_in[11];
  const float* mlp_b2 = (const float*)d_in[12];

  char* ws = (char*)d_ws;
  unsigned short* wpack = (unsigned short*)(ws);
  float*          bqs   = (float*)(ws + 393216);
  unsigned short* qkv   = (unsigned short*)(ws + 524288);
  unsigned short* attnA = (unsigned short*)(ws + 13107200);
  float* out = (float*)d_out;

  hipLaunchKernelGGL(k_pack, dim3(96), dim3(256), 0, stream,
                     qkv_w, qkv_b, proj_w, mlp_w1, mlp_w2, wpack, bqs);
  hipLaunchKernelGGL(k_qkv, dim3(256), dim3(512), 0, stream,
                     x, ln1_g, ln1_b, wpack, bqs, qkv);
  hipLaunchKernelGGL(k_attn, dim3(512), dim3(512), 0, stream, qkv, attnA);
  hipLaunchKernelGGL(k_fused, dim3(512), dim3(512), 0, stream,
                     attnA, x, wpack, proj_b, ln2_g, ln2_b,
                     mlp_b1, mlp_b2, out);
}

// Round 19
// 77.777 us; speedup vs baseline: 1.0807x; 1.0807x over previous
//
#include <hip/hip_runtime.h>
#include <hip/hip_bf16.h>
#include <math.h>

#define NSEQ   4096
#define CDIM   128
#define HD     32

typedef __attribute__((ext_vector_type(8))) short short8;
typedef __attribute__((ext_vector_type(4))) short short4v;
typedef __attribute__((ext_vector_type(4))) float f32x4;

#define QSCL (0.17677669529663687f * 1.4426950408889634f)  // 1/sqrt(32)*log2(e)

__device__ inline unsigned short f2bf(float f){
  union { float f; unsigned u; } v; v.f = f;
  return (unsigned short)((v.u + 0x7fffu + ((v.u >> 16) & 1u)) >> 16);
}
__device__ inline float bf2f(unsigned short u){
  union { unsigned u; float f; } v; v.u = ((unsigned)u) << 16;
  return v.f;
}
__device__ inline void gload_lds16(const unsigned short* g, unsigned short* l){
  __builtin_amdgcn_global_load_lds(
      (const __attribute__((address_space(1))) void*)g,
      (__attribute__((address_space(3))) void*)l, 16, 0, 0);
}

// ---- ws layout (bytes) -----------------------------------------------------
// 0        : wpack u16 [196608] (wq@0, wp@49152, w1@65536, w2@131072)
// 393216   : bqs f32 [384]
// 524288   : qkv u16 48 planes x 131072 (Q[0..15] rowmajor, Kfrag[16..31], Vfrag[32..47])
// 13107200 : part_ob bf16 [2][16][4096][32] (8.4MB)
// 29884416 : part_l f32 [2][16][4096] (0.5MB)

// ---------------- K0: pack weights to MFMA B-fragment layout ----------------
__global__ __launch_bounds__(256) void k_pack(
    const float* __restrict__ qkv_w, const float* __restrict__ qkv_b,
    const float* __restrict__ proj_w, const float* __restrict__ mlp_w1,
    const float* __restrict__ mlp_w2, unsigned short* __restrict__ wpack,
    float* __restrict__ bqs)
{
  const int gt = blockIdx.x * 256 + threadIdx.x;
  const int tile = gt >> 6, lane = gt & 63;
  const float* src; int N, KT, toff, dstoff; float scale = 1.f;
  if (tile < 96)       { src = qkv_w;  N = 384; KT = 4;  toff = tile;       dstoff = 0; }
  else if (tile < 128) { src = proj_w; N = 128; KT = 4;  toff = tile - 96;  dstoff = 49152; }
  else if (tile < 256) { src = mlp_w1; N = 512; KT = 4;  toff = tile - 128; dstoff = 65536; }
  else                 { src = mlp_w2; N = 128; KT = 16; toff = tile - 256; dstoff = 131072; }
  const int ct = toff / KT, kt = toff % KT;
  if (tile < 96 && ct < 8) scale = QSCL;   // Q columns
  const int row0 = kt * 32 + (lane >> 4) * 8, col = ct * 16 + (lane & 15);
  short8 v;
  #pragma unroll
  for (int i = 0; i < 8; i++)
    v[i] = (short)f2bf(src[(size_t)(row0 + i) * N + col] * scale);
  *(short8*)(wpack + dstoff + ((size_t)(ct * KT + kt) * 64 + lane) * 8) = v;
  if (gt < 384) bqs[gt] = qkv_b[gt] * (gt < 128 ? QSCL : 1.f);
}

// ---------------- K1: LN1 + QKV MFMA GEMM (64 tokens/block, 256 blocks) -----
__global__ __launch_bounds__(512) void k_qkv(
    const float* __restrict__ x, const float* __restrict__ g,
    const float* __restrict__ b, const unsigned short* __restrict__ wpack,
    const float* __restrict__ bqs, unsigned short* __restrict__ qkv)
{
  __shared__ unsigned short xn[64 * 128];
  const int tid = threadIdx.x;
  const int tok0 = blockIdx.x * 64;
  {
    const int grp = tid >> 5, l = tid & 31;
    #pragma unroll
    for (int it = 0; it < 4; it++){
      const int t = it * 16 + grp;
      const float4 xv = *(const float4*)(x + (size_t)(tok0 + t) * 128 + l * 4);
      float s  = xv.x + xv.y + xv.z + xv.w;
      float s2 = xv.x*xv.x + xv.y*xv.y + xv.z*xv.z + xv.w*xv.w;
      #pragma unroll
      for (int m = 1; m <= 16; m <<= 1){ s += __shfl_xor(s, m); s2 += __shfl_xor(s2, m); }
      const float mu = s * (1.f/128.f);
      const float rs = rsqrtf(s2 * (1.f/128.f) - mu*mu + 1e-5f);
      const int e = l * 4;
      const float4 gv = *(const float4*)(g + e), bv = *(const float4*)(b + e);
      short4v pk;
      pk[0] = (short)f2bf((xv.x - mu)*rs*gv.x + bv.x);
      pk[1] = (short)f2bf((xv.y - mu)*rs*gv.y + bv.y);
      pk[2] = (short)f2bf((xv.z - mu)*rs*gv.z + bv.z);
      pk[3] = (short)f2bf((xv.w - mu)*rs*gv.w + bv.w);
      const int bl = l >> 1;
      const int slot = bl * 64 + (t & 48) + ((t & 15) ^ bl);
      *(short4v*)(xn + slot * 8 + (l & 1) * 4) = pk;
    }
  }
  __syncthreads();
  const int wv = tid >> 6, lane = tid & 63, r = lane & 15, cg = lane >> 4;
  const int rt = wv & 3, ct0 = (wv >> 2) * 12;
  short8 af[4];
  #pragma unroll
  for (int kt = 0; kt < 4; kt++){
    const int bl = kt * 4 + cg;
    const int slot = bl * 64 + rt * 16 + (r ^ bl);
    af[kt] = *(const short8*)(xn + slot * 8);
  }
  const int bidx = tok0 >> 12, nloc = (tok0 & (NSEQ - 1)) + rt * 16 + cg * 4;
  for (int ct = ct0; ct < ct0 + 12; ct++){
    f32x4 acc = {0.f, 0.f, 0.f, 0.f};
    const unsigned short* bp = wpack + ((size_t)(ct * 4) * 64 + lane) * 8;
    #pragma unroll
    for (int kt = 0; kt < 4; kt++)
      acc = __builtin_amdgcn_mfma_f32_16x16x32_bf16(af[kt], *(const short8*)(bp + kt * 512), acc, 0, 0, 0);
    const int col = ct * 16 + r;
    const float bi = bqs[col];
    if (ct < 8){                                   // Q: row-major [n][32]
      const int cc = col & 127, h = cc >> 5, d = cc & 31;
      unsigned short* plane = qkv + ((size_t)bidx * 4 + h) * (NSEQ * HD);
      #pragma unroll
      for (int reg = 0; reg < 4; reg++)
        plane[(size_t)(nloc + reg) * HD + d] = f2bf(acc[reg] + bi);
    } else if (ct < 16){                           // K: A-fragment layout per 16-row tile
      const int cc = col & 127, h = cc >> 5, d = cc & 31;
      unsigned short* plane = qkv + ((size_t)16 + bidx * 4 + h) * (NSEQ * HD);
      const int t16 = ((tok0 & (NSEQ - 1)) >> 4) + rt;
      #pragma unroll
      for (int reg = 0; reg < 4; reg++)
        plane[(size_t)t16 * 512 + (d >> 3) * 128 + (cg * 4 + reg) * 8 + (d & 7)]
            = f2bf(acc[reg] + bi);
    } else {                                       // V: PV-fragment layout
      const int vct = ct - 16, h = vct >> 1, half = vct & 1;
      unsigned short* plane = qkv + ((size_t)32 + bidx * 4 + h) * (NSEQ * HD);
      const size_t ntile = (size_t)((tok0 & (NSEQ - 1)) >> 5) + (rt >> 1);
      const size_t vo = (ntile * 2 + half) * 512 + lane * 8 + (rt & 1) * 4;
      short4v pk;
      #pragma unroll
      for (int reg = 0; reg < 4; reg++) pk[reg] = (short)f2bf(acc[reg] + bi);
      *(short4v*)(plane + vo) = pk;
    }
  }
}

// ---------------- K2: flash attention, KVBLK=64, 8-wave blocks --------------
// grid (16, 2, 16); block 512 (8 waves). Block: 256 q rows, chunk 2048 keys.
// Each wave stages exactly ONE 1KB global_load_lds per iter (waves 0-3: K
// quarters, 4-7: V quarters) -> counted wait vmcnt(2), 3-deep ring.
__global__ __launch_bounds__(512, 4) void k_attn(
    const unsigned short* __restrict__ qkv, unsigned short* __restrict__ part_ob,
    float* __restrict__ part_l)
{
  __shared__ unsigned short sbuf[16384];   // 32KB: 4 slots x (K 4KB + V 4KB)
  const int tid = threadIdx.x;
  const int lane = tid & 63, wv = tid >> 6;
  const int chunk = blockIdx.y, bh = blockIdx.z;
  const int qbase = blockIdx.x * 256 + wv * 32;
  const int kv0 = chunk * 2048;
  const unsigned short* Q  = qkv + (size_t)bh * (NSEQ * HD);
  const unsigned short* Kc = qkv + (size_t)(16 + bh) * (NSEQ * HD) + (size_t)kv0 * HD;
  const unsigned short* Vc = qkv + (size_t)(32 + bh) * (NSEQ * HD) + (size_t)kv0 * HD;
  const int r = lane & 15, cg = lane >> 4;
  const short8 qf0 = *(const short8*)(Q + (size_t)(qbase + r) * HD + cg * 8);
  const short8 qf1 = *(const short8*)(Q + (size_t)(qbase + 16 + r) * HD + cg * 8);
  // staging: wave w<4 loads K quarter w; wave w>=4 loads V quarter (w-4)
  const unsigned short* gsrc = (wv < 4 ? Kc + wv * 512 : Vc + (wv - 4) * 512) + lane * 8;
  const int dst = wv * 512;                // u16 offset within slot (K then V)
  union { unsigned u[4]; short8 s; } onesu;
  onesu.u[0] = 0x3F803F80u; onesu.u[1] = 0x3F803F80u;
  onesu.u[2] = 0x3F803F80u; onesu.u[3] = 0x3F803F80u;
  const short8 vones = onesu.s;
  f32x4 o00 = {0.f,0.f,0.f,0.f}, o01 = {0.f,0.f,0.f,0.f};
  f32x4 o10 = {0.f,0.f,0.f,0.f}, o11 = {0.f,0.f,0.f,0.f};
  f32x4 lacc0 = {0.f,0.f,0.f,0.f}, lacc1 = {0.f,0.f,0.f,0.f};
  const f32x4 zero = {0.f,0.f,0.f,0.f};
  // prologue: 3-deep prefetch (slots 0,1,2) -- 1 load per wave per slot
  gload_lds16(gsrc,        sbuf + 0 * 4096 + dst);
  gload_lds16(gsrc + 2048, sbuf + 1 * 4096 + dst);
  gload_lds16(gsrc + 4096, sbuf + 2 * 4096 + dst);
  for (int t = 0; t < 32; t++){
    // own load(t) landed (vmcnt(2): exactly 3 outstanding, oldest is t's)
    // AND own prior-iter LDS reads done, BEFORE signaling the barrier.
    asm volatile("s_waitcnt vmcnt(2) lgkmcnt(0)" ::: "memory");
    __builtin_amdgcn_sched_barrier(0);
    __builtin_amdgcn_s_barrier();
    __builtin_amdgcn_sched_barrier(0);
    const int tn = (t + 3 > 31) ? 31 : t + 3;   // clamped dummy keeps vmcnt uniform
    gload_lds16(gsrc + (size_t)tn * 2048, sbuf + ((t + 3) & 3) * 4096 + dst);
    const unsigned short* skb = sbuf + (t & 3) * 4096;
    const unsigned short* svb = skb + 2048;
    #pragma unroll
    for (int ktp = 0; ktp < 2; ktp++){
      const short8 kaa = *(const short8*)(skb + (ktp * 2 + 0) * 512 + lane * 8);
      const short8 kab = *(const short8*)(skb + (ktp * 2 + 1) * 512 + lane * 8);
      const short8 va0 = *(const short8*)(svb + (ktp * 2 + 0) * 512 + lane * 8);
      const short8 va1 = *(const short8*)(svb + (ktp * 2 + 1) * 512 + lane * 8);
      const f32x4 s00 = __builtin_amdgcn_mfma_f32_16x16x32_bf16(kaa, qf0, zero, 0, 0, 0);
      const f32x4 s01 = __builtin_amdgcn_mfma_f32_16x16x32_bf16(kab, qf0, zero, 0, 0, 0);
      const f32x4 s10 = __builtin_amdgcn_mfma_f32_16x16x32_bf16(kaa, qf1, zero, 0, 0, 0);
      const f32x4 s11 = __builtin_amdgcn_mfma_f32_16x16x32_bf16(kab, qf1, zero, 0, 0, 0);
      float p00[4], p01[4], p10[4], p11[4];
      #pragma unroll
      for (int i = 0; i < 4; i++){
        p00[i] = __builtin_amdgcn_exp2f(s00[i]);
        p01[i] = __builtin_amdgcn_exp2f(s01[i]);
        p10[i] = __builtin_amdgcn_exp2f(s10[i]);
        p11[i] = __builtin_amdgcn_exp2f(s11[i]);
      }
      unsigned c0, c1, c2, c3, c4, c5, c6, c7;
      asm("v_cvt_pk_bf16_f32 %0, %1, %2" : "=v"(c0) : "v"(p00[0]), "v"(p00[1]));
      asm("v_cvt_pk_bf16_f32 %0, %1, %2" : "=v"(c1) : "v"(p00[2]), "v"(p00[3]));
      asm("v_cvt_pk_bf16_f32 %0, %1, %2" : "=v"(c2) : "v"(p01[0]), "v"(p01[1]));
      asm("v_cvt_pk_bf16_f32 %0, %1, %2" : "=v"(c3) : "v"(p01[2]), "v"(p01[3]));
      asm("v_cvt_pk_bf16_f32 %0, %1, %2" : "=v"(c4) : "v"(p10[0]), "v"(p10[1]));
      asm("v_cvt_pk_bf16_f32 %0, %1, %2" : "=v"(c5) : "v"(p10[2]), "v"(p10[3]));
      asm("v_cvt_pk_bf16_f32 %0, %1, %2" : "=v"(c6) : "v"(p11[0]), "v"(p11[1]));
      asm("v_cvt_pk_bf16_f32 %0, %1, %2" : "=v"(c7) : "v"(p11[2]), "v"(p11[3]));
      union { unsigned u[4]; short8 s; } pa, pb;
      pa.u[0] = c0; pa.u[1] = c1; pa.u[2] = c2; pa.u[3] = c3;
      pb.u[0] = c4; pb.u[1] = c5; pb.u[2] = c6; pb.u[3] = c7;
      o00 = __builtin_amdgcn_mfma_f32_16x16x32_bf16(va0, pa.s, o00, 0, 0, 0);
      o01 = __builtin_amdgcn_mfma_f32_16x16x32_bf16(va1, pa.s, o01, 0, 0, 0);
      o10 = __builtin_amdgcn_mfma_f32_16x16x32_bf16(va0, pb.s, o10, 0, 0, 0);
      o11 = __builtin_amdgcn_mfma_f32_16x16x32_bf16(va1, pb.s, o11, 0, 0, 0);
      lacc0 = __builtin_amdgcn_mfma_f32_16x16x32_bf16(vones, pa.s, lacc0, 0, 0, 0);
      lacc1 = __builtin_amdgcn_mfma_f32_16x16x32_bf16(vones, pb.s, lacc1, 0, 0, 0);
    }
  }
  // drain trailing dummy LDS-DMA writes before workgroup exit
  asm volatile("s_waitcnt vmcnt(0)" ::: "memory");
  const float ls0 = lacc0[0], ls1 = lacc1[0];   // all regs/lane-groups equal
  unsigned short* po = part_ob + (((size_t)(chunk * 16 + bh) * NSEQ) + qbase + r) * HD;
  short4v w0, w1, w2, w3;
  #pragma unroll
  for (int j = 0; j < 4; j++){
    w0[j] = (short)f2bf(o00[j]); w1[j] = (short)f2bf(o01[j]);
    w2[j] = (short)f2bf(o10[j]); w3[j] = (short)f2bf(o11[j]);
  }
  *(short4v*)(po + cg * 4)              = w0;
  *(short4v*)(po + 16 + cg * 4)         = w1;
  *(short4v*)(po + 16 * HD + cg * 4)    = w2;
  *(short4v*)(po + 16 * HD + 16 + cg * 4) = w3;
  if (lane < 16){
    part_l[(size_t)(chunk * 16 + bh) * NSEQ + qbase + r] = ls0;
    part_l[(size_t)(chunk * 16 + bh) * NSEQ + qbase + 16 + r] = ls1;
  }
}

// ---------------- K3: fused reduce+proj+LN2+MLP1+GELU+MLP2 (32 tok/block) ---
// 512 blocks, 512 threads, 48KB LDS. sbb in bf16; afh shared between the
// attn A-frag (A0/A) and LN2 output (B/C). GELU via tanh-approx.
__global__ __launch_bounds__(512, 6) void k_fused(
    const unsigned short* __restrict__ part_ob, const float* __restrict__ part_l,
    const float* __restrict__ x, const unsigned short* __restrict__ wpack,
    const float* __restrict__ pb, const float* __restrict__ g2,
    const float* __restrict__ b2, const float* __restrict__ b1,
    const float* __restrict__ b2m, float* __restrict__ out)
{
  __shared__ unsigned short afh[2][2048];    //  8KB: afA (A0/A), then hfr (B/C)
  __shared__ unsigned short sbb[32 * 128];   //  8KB residual, bf16
  __shared__ unsigned short afr[2][8192];    // 32KB GELU acts, A-frag layout
  const int tid = threadIdx.x, tok0 = blockIdx.x * 32;
  const int wv = tid >> 6, lane = tid & 63, r = lane & 15, cg = lane >> 4;
  const int rt = wv & 1, cgp = wv >> 1;
  const int bidx = tok0 >> 12;
  // ---- phase A0: cooperative softmax-reduce -> afh (A-frag layout)
  {
    const int row = tid >> 4;                  // 32 rows, 16 threads/row
    const int c0 = (tid & 15) * 8;             // 8-col run
    const int kt = c0 >> 5, cgf = (c0 >> 3) & 3;
    const int bh = bidx * 4 + kt;
    const size_t q = (size_t)((tok0 & (NSEQ - 1)) + row);
    float s8[8] = {0.f,0.f,0.f,0.f,0.f,0.f,0.f,0.f};
    float lsum = 0.f;
    #pragma unroll
    for (int c = 0; c < 2; c++){
      const short8 v = *(const short8*)(part_ob +
          (((size_t)(c * 16 + bh) * NSEQ) + q) * HD + (c0 & 31));
      #pragma unroll
      for (int i = 0; i < 8; i++) s8[i] += bf2f((unsigned short)v[i]);
      lsum += part_l[(size_t)(c * 16 + bh) * NSEQ + q];
    }
    const float inv = 1.f / lsum;
    short8 pk;
    #pragma unroll
    for (int i = 0; i < 8; i++) pk[i] = (short)f2bf(s8[i] * inv);
    *(short8*)(&afh[row >> 4][(kt * 4 + cgf) * 128 + (row & 15) * 8]) = pk;
  }
  __syncthreads();
  // ---- phase A: proj MFMA + bias + residual -> sbb (bf16)
  {
    short8 af[4];
    #pragma unroll
    for (int kt = 0; kt < 4; kt++)
      af[kt] = *(const short8*)(&afh[rt][(kt * 4 + cg) * 128 + r * 8]);
    const unsigned short* wp = wpack + 49152;
    for (int ct = cgp * 2; ct < cgp * 2 + 2; ct++){
      f32x4 acc = {0.f, 0.f, 0.f, 0.f};
      const unsigned short* bp = wp + ((size_t)(ct * 4) * 64 + lane) * 8;
      #pragma unroll
      for (int kt = 0; kt < 4; kt++)
        acc = __builtin_amdgcn_mfma_f32_16x16x32_bf16(af[kt], *(const short8*)(bp + kt * 512), acc, 0, 0, 0);
      const int col = ct * 16 + r;
      const float bi = pb[col];
      #pragma unroll
      for (int reg = 0; reg < 4; reg++){
        const int tl = rt * 16 + cg * 4 + reg;
        sbb[tl * 128 + col] = f2bf(acc[reg] + bi + x[(size_t)(tok0 + tl) * 128 + col]);
      }
    }
  }
  __syncthreads();
  // ---- phase B: LN2(sbb) -> afh (A-frag layout; afA is dead now)
  {
    const int grp = tid >> 5, l = tid & 31;
    #pragma unroll
    for (int it = 0; it < 2; it++){
      const int t = it * 16 + grp;
      const short4v xb = *(const short4v*)(sbb + t * 128 + l * 4);
      const float x0 = bf2f((unsigned short)xb[0]), x1 = bf2f((unsigned short)xb[1]);
      const float x2 = bf2f((unsigned short)xb[2]), x3 = bf2f((unsigned short)xb[3]);
      float s  = x0 + x1 + x2 + x3;
      float s2 = x0*x0 + x1*x1 + x2*x2 + x3*x3;
      #pragma unroll
      for (int m = 1; m <= 16; m <<= 1){ s += __shfl_xor(s, m); s2 += __shfl_xor(s2, m); }
      const float mu = s * (1.f/128.f);
      const float rs = rsqrtf(s2 * (1.f/128.f) - mu*mu + 1e-5f);
      const int e = l * 4;
      const float4 gv = *(const float4*)(g2 + e), bv = *(const float4*)(b2 + e);
      short4v pk;
      pk[0] = (short)f2bf((x0 - mu)*rs*gv.x + bv.x);
      pk[1] = (short)f2bf((x1 - mu)*rs*gv.y + bv.y);
      pk[2] = (short)f2bf((x2 - mu)*rs*gv.z + bv.z);
      pk[3] = (short)f2bf((x3 - mu)*rs*gv.w + bv.w);
      *(short4v*)(&afh[t >> 4][(e >> 3) * 128 + (t & 15) * 8 + (e & 7)]) = pk;
    }
  }
  __syncthreads();
  // ---- phase C: MLP1 + GELU(tanh approx) -> afr (A-frag layout)
  {
    short8 hf[4];
    #pragma unroll
    for (int kt = 0; kt < 4; kt++)
      hf[kt] = *(const short8*)(&afh[rt][(kt * 4 + cg) * 128 + r * 8]);
    const unsigned short* w1 = wpack + 65536;
    for (int ct = cgp * 8; ct < cgp * 8 + 8; ct++){
      f32x4 acc = {0.f, 0.f, 0.f, 0.f};
      const unsigned short* bp = w1 + ((size_t)(ct * 4) * 64 + lane) * 8;
      #pragma unroll
      for (int kt = 0; kt < 4; kt++)
        acc = __builtin_amdgcn_mfma_f32_16x16x32_bf16(hf[kt], *(const short8*)(bp + kt * 512), acc, 0, 0, 0);
      const int col = ct * 16 + r;
      const float bi = b1[col];
      #pragma unroll
      for (int reg = 0; reg < 4; reg++){
        const float v = acc[reg] + bi;
        // gelu(v) = v / (1 + exp2(-(a*v + b*v^3))), a=2.3022077, b=0.10294324
        const float u = v * (2.3022077f + 0.10294324f * v * v);
        const float ge = v * __builtin_amdgcn_rcpf(1.f + __builtin_amdgcn_exp2f(-u));
        afr[rt][(col >> 3) * 128 + (cg * 4 + reg) * 8 + (col & 7)] = f2bf(ge);
      }
    }
  }
  __syncthreads();
  // ---- phase D: MLP2 + residual (sbb) -> out
  {
    const unsigned short* w2 = wpack + 131072;
    f32x4 acc0 = {0.f,0.f,0.f,0.f}, acc1 = {0.f,0.f,0.f,0.f};
    for (int kt = 0; kt < 16; kt++){
      const short8 a3 = *(const short8*)(&afr[rt][(kt * 4 + cg) * 128 + r * 8]);
      const unsigned short* bp0 = w2 + ((size_t)((cgp * 2 + 0) * 16 + kt) * 64 + lane) * 8;
      const unsigned short* bp1 = w2 + ((size_t)((cgp * 2 + 1) * 16 + kt) * 64 + lane) * 8;
      acc0 = __builtin_amdgcn_mfma_f32_16x16x32_bf16(a3, *(const short8*)(bp0), acc0, 0, 0, 0);
      acc1 = __builtin_amdgcn_mfma_f32_16x16x32_bf16(a3, *(const short8*)(bp1), acc1, 0, 0, 0);
    }
    #pragma unroll
    for (int c = 0; c < 2; c++){
      const f32x4 acc = c ? acc1 : acc0;
      const int col = (cgp * 2 + c) * 16 + r;
      const float bi = b2m[col];
      #pragma unroll
      for (int reg = 0; reg < 4; reg++){
        const int tl = rt * 16 + cg * 4 + reg;
        out[(size_t)(tok0 + tl) * 128 + col] = acc[reg] + bi + bf2f(sbb[tl * 128 + col]);
      }
    }
  }
}

extern "C" void kernel_launch(void* const* d_in, const int* in_sizes, int n_in,
                              void* d_out, int out_size, void* d_ws, size_t ws_size,
                              hipStream_t stream)
{
  const float* x      = (const float*)d_in[0];
  const float* ln1_g  = (const float*)d_in[1];
  const float* ln1_b  = (const float*)d_in[2];
  const float* qkv_w  = (const float*)d_in[3];
  const float* qkv_b  = (const float*)d_in[4];
  const float* proj_w = (const float*)d_in[5];
  const float* proj_b = (const float*)d_in[6];
  const float* ln2_g  = (const float*)d_in[7];
  const float* ln2_b  = (const float*)d_in[8];
  const float* mlp_w1 = (const float*)d_in[9];
  const float* mlp_b1 = (const float*)d_in[10];
  const float* mlp_w2 = (const float*)d_in[11];
  const float* mlp_b2 = (const float*)d_in[12];

  char* ws = (char*)d_ws;
  unsigned short* wpack   = (unsigned short*)(ws);
  float*          bqs     = (float*)(ws + 393216);
  unsigned short* qkv     = (unsigned short*)(ws + 524288);
  unsigned short* part_ob = (unsigned short*)(ws + 13107200);
  float*          part_l  = (float*)(ws + 29884416);
  float* out = (float*)d_out;

  hipLaunchKernelGGL(k_pack, dim3(96), dim3(256), 0, stream,
                     qkv_w, qkv_b, proj_w, mlp_w1, mlp_w2, wpack, bqs);
  hipLaunchKernelGGL(k_qkv, dim3(256), dim3(512), 0, stream,
                     x, ln1_g, ln1_b, wpack, bqs, qkv);
  hipLaunchKernelGGL(k_attn, dim3(16, 2, 16), dim3(512), 0, stream,
                     qkv, part_ob, part_l);
  hipLaunchKernelGGL(k_fused, dim3(512), dim3(512), 0, stream,
                     part_ob, part_l, x, wpack, proj_b, ln2_g, ln2_b,
                     mlp_b1, mlp_b2, out);
}